// Round 8
// baseline (216.231 us; speedup 1.0000x reference)
//
#include <hip/hip_runtime.h>
#include <stdint.h>

#define EMB 512
#define SEQ 2048
#define MB 4
#define NH 8
#define HD 64
#define ROWS (MB*SEQ)          // 8192
#define MARGIN 0.02f
#define CAP 65536
#define LOG2E 1.44269504f
#define EXPB (-17.3123405f)    // -12 * log2(e)

typedef unsigned short u16;
typedef __attribute__((ext_vector_type(8))) short bf16x8;   // 8 bf16 (4 VGPRs)
typedef __attribute__((ext_vector_type(4))) float f32x4;
typedef __attribute__((ext_vector_type(2))) unsigned int u32x2;
typedef __attribute__((ext_vector_type(4))) unsigned int u32x4;

union Frag { u32x2 u[2]; bf16x8 v; };
union Frag4 { unsigned u[4]; bf16x8 v; };

__device__ __forceinline__ u16 f2bf(float f) {
  union { float f; unsigned u; } a; a.f = f;
  unsigned r = a.u + 0x7FFFu + ((a.u >> 16) & 1u);  // RNE
  return (u16)(r >> 16);
}
__device__ __forceinline__ float bflo(unsigned u) {
  union { unsigned u; float f; } c; c.u = u << 16; return c.f;
}
__device__ __forceinline__ float bfhi(unsigned u) {
  union { unsigned u; float f; } c; c.u = u & 0xffff0000u; return c.f;
}
// async global->LDS, 16B per lane; LDS dest = wave-uniform base + lane*16
__device__ __forceinline__ void gld16(const void* g, void* l) {
  __builtin_amdgcn_global_load_lds(
      (const __attribute__((address_space(1))) void*)g,
      (__attribute__((address_space(3))) void*)l, 16, 0, 0);
}

// ---------------- fused prep: 4 weight transposes (blocks 0..1791) + LN1 (1792..3839) ----

__global__ __launch_bounds__(256) void k_prep(
    const float* __restrict__ x, const float* __restrict__ g1, const float* __restrict__ be1,
    const float* __restrict__ wq, const float* __restrict__ wk,
    const float* __restrict__ wv, const float* __restrict__ w1,
    u16* __restrict__ n1, u16* __restrict__ wqkvT, u16* __restrict__ w1T,
    int* __restrict__ cnt) {
  __shared__ float tile[32][33];
  int b = blockIdx.x, tid = threadIdx.x;
  if (b < 1792) {
    const float* src; u16* dst; int N, bx, by;
    if (b < 768) {
      int z = b >> 8, rem = b & 255; bx = rem & 15; by = rem >> 4; N = 512;
      src = (z == 0) ? wq : ((z == 1) ? wk : wv);
      dst = wqkvT + z * 512 * 512;
    } else {
      int rem = b - 768; bx = rem & 63; by = rem >> 6; N = 2048;
      src = w1; dst = w1T;
    }
    int tx = tid & 31, ty = tid >> 5;
    int k0 = by * 32, n0 = bx * 32;
    for (int i = 0; i < 32; i += 8)
      tile[ty + i][tx] = src[(size_t)(k0 + ty + i) * N + n0 + tx];
    __syncthreads();
    for (int i = 0; i < 32; i += 8)
      dst[(size_t)(n0 + ty + i) * 512 + k0 + tx] = f2bf(tile[tx][ty + i]);
  } else {
    if (b == 1792 && tid < 2) cnt[tid] = 0;
    int wid = tid >> 6, lane = tid & 63;
    int row = (b - 1792) * 4 + wid;
    const float* xr = x + (size_t)row * EMB + lane * 8;
    f32x4 v0 = *(const f32x4*)xr;
    f32x4 v1 = *(const f32x4*)(xr + 4);
    float s = v0.x+v0.y+v0.z+v0.w + v1.x+v1.y+v1.z+v1.w;
    float q = v0.x*v0.x+v0.y*v0.y+v0.z*v0.z+v0.w*v0.w
            + v1.x*v1.x+v1.y*v1.y+v1.z*v1.z+v1.w*v1.w;
    #pragma unroll
    for (int o = 1; o < 64; o <<= 1) { s += __shfl_xor(s, o); q += __shfl_xor(q, o); }
    float mu = s * (1.0f/512.0f);
    float rs = 1.0f / sqrtf(q * (1.0f/512.0f) - mu*mu + 1e-5f);
    f32x4 ga = *(const f32x4*)(g1 + lane*8), gb = *(const f32x4*)(g1 + lane*8 + 4);
    f32x4 ba = *(const f32x4*)(be1 + lane*8), bb = *(const f32x4*)(be1 + lane*8 + 4);
    union { u16 h[8]; u32x4 v; } o8;
    o8.h[0] = f2bf((v0.x-mu)*rs*ga.x + ba.x); o8.h[1] = f2bf((v0.y-mu)*rs*ga.y + ba.y);
    o8.h[2] = f2bf((v0.z-mu)*rs*ga.z + ba.z); o8.h[3] = f2bf((v0.w-mu)*rs*ga.w + ba.w);
    o8.h[4] = f2bf((v1.x-mu)*rs*gb.x + bb.x); o8.h[5] = f2bf((v1.y-mu)*rs*gb.y + bb.y);
    o8.h[6] = f2bf((v1.z-mu)*rs*gb.z + bb.z); o8.h[7] = f2bf((v1.w-mu)*rs*gb.w + bb.w);
    *(u32x4*)(n1 + (size_t)row * EMB + lane * 8) = o8.v;
  }
}

// x2 = x + att(bf16) ; n2 = LN(x2) ; out = x2 + b2
__global__ __launch_bounds__(256) void k_ln2(const float* __restrict__ x,
    const u16* __restrict__ att, const float* __restrict__ g, const float* __restrict__ b,
    const float* __restrict__ b2, float* __restrict__ x2, u16* __restrict__ n2,
    float* __restrict__ out) {
  int wid = threadIdx.x >> 6, lane = threadIdx.x & 63;
  int row = blockIdx.x * 4 + wid;
  size_t base = (size_t)row * EMB + lane * 8;
  u32x4 av = *(const u32x4*)(att + base);
  f32x4 t0, t1;
  t0.x = bflo(av.x); t0.y = bfhi(av.x); t0.z = bflo(av.y); t0.w = bfhi(av.y);
  t1.x = bflo(av.z); t1.y = bfhi(av.z); t1.z = bflo(av.w); t1.w = bfhi(av.w);
  f32x4 v0 = *(const f32x4*)(x + base)     + t0;
  f32x4 v1 = *(const f32x4*)(x + base + 4) + t1;
  *(f32x4*)(x2 + base) = v0;
  *(f32x4*)(x2 + base + 4) = v1;
  *(f32x4*)(out + base)     = v0 + *(const f32x4*)(b2 + lane*8);
  *(f32x4*)(out + base + 4) = v1 + *(const f32x4*)(b2 + lane*8 + 4);
  float s = v0.x+v0.y+v0.z+v0.w + v1.x+v1.y+v1.z+v1.w;
  float q = v0.x*v0.x+v0.y*v0.y+v0.z*v0.z+v0.w*v0.w
          + v1.x*v1.x+v1.y*v1.y+v1.z*v1.z+v1.w*v1.w;
  #pragma unroll
  for (int o = 1; o < 64; o <<= 1) { s += __shfl_xor(s, o); q += __shfl_xor(q, o); }
  float mu = s * (1.0f/512.0f);
  float rs = 1.0f / sqrtf(q * (1.0f/512.0f) - mu*mu + 1e-5f);
  f32x4 ga = *(const f32x4*)(g + lane*8), gb = *(const f32x4*)(g + lane*8 + 4);
  f32x4 ba = *(const f32x4*)(b + lane*8), bb = *(const f32x4*)(b + lane*8 + 4);
  union { u16 h[8]; u32x4 v; } o8;
  o8.h[0] = f2bf((v0.x-mu)*rs*ga.x + ba.x); o8.h[1] = f2bf((v0.y-mu)*rs*ga.y + ba.y);
  o8.h[2] = f2bf((v0.z-mu)*rs*ga.z + ba.z); o8.h[3] = f2bf((v0.w-mu)*rs*ga.w + ba.w);
  o8.h[4] = f2bf((v1.x-mu)*rs*gb.x + bb.x); o8.h[5] = f2bf((v1.y-mu)*rs*gb.y + bb.y);
  o8.h[6] = f2bf((v1.z-mu)*rs*gb.z + bb.z); o8.h[7] = f2bf((v1.w-mu)*rs*gb.w + bb.w);
  *(u32x4*)(n2 + (size_t)row * EMB + lane * 8) = o8.v;
}

// -------- GEMM core v3: 2 K-tiles per barrier, dbuf (flash-v6 mechanism), 9 barriers --------
// Same K-tile consumption order as r6 -> bit-identical accumulation.
#define G_STAGE(BUF, T0)                                                       \
  do {                                                                         \
    int ko = (T0) * 32;                                                        \
    gld16(gA0 + ko,      &As[BUF][0][(wid * 32) * 32]);                        \
    gld16(gA1 + ko,      &As[BUF][0][(wid * 32 + 16) * 32]);                   \
    gld16(gA0 + ko + 32, &As[BUF][1][(wid * 32) * 32]);                        \
    gld16(gA1 + ko + 32, &As[BUF][1][(wid * 32 + 16) * 32]);                   \
    gld16(gB0 + ko,      &Bs[BUF][0][(wid * 32) * 32]);                        \
    gld16(gB1 + ko,      &Bs[BUF][0][(wid * 32 + 16) * 32]);                   \
    gld16(gB0 + ko + 32, &Bs[BUF][1][(wid * 32) * 32]);                        \
    gld16(gB1 + ko + 32, &Bs[BUF][1][(wid * 32 + 16) * 32]);                   \
  } while (0)

#define G_INNER(CUR, SUB)                                                      \
  do {                                                                         \
    bf16x8 af[4], bf[4];                                                       \
    _Pragma("unroll")                                                          \
    for (int i = 0; i < 4; i++) {                                              \
      af[i] = *(const bf16x8*)&As[CUR][SUB][(wm + i * 16 + ln15) * 32 + quad * 8]; \
      bf[i] = *(const bf16x8*)&Bs[CUR][SUB][(wn + i * 16 + ln15) * 32 + quad * 8]; \
    }                                                                          \
    _Pragma("unroll")                                                          \
    for (int i = 0; i < 4; i++)                                                \
      _Pragma("unroll")                                                        \
      for (int j = 0; j < 4; j++)                                              \
        acc[i][j] = __builtin_amdgcn_mfma_f32_16x16x32_bf16(af[i], bf[j],      \
                                                            acc[i][j], 0, 0, 0);\
  } while (0)

#define G_STEP(CUR, S)                                                         \
  do {                                                                         \
    __syncthreads();                                                           \
    if ((S) < 7) G_STAGE((CUR) ^ 1, 2 * (S) + 2);                              \
    G_INNER(CUR, 0);                                                           \
    G_INNER(CUR, 1);                                                           \
  } while (0)

#define GEMM_CORE(A_, Bt_, m0_, n0_)                                           \
  __shared__ u16 As[2][2][128 * 32];                                           \
  __shared__ u16 Bs[2][2][128 * 32];                                           \
  int tid = threadIdx.x;                                                       \
  int wid = tid >> 6, lane = tid & 63;                                         \
  int quad = lane >> 4, ln15 = lane & 15;                                      \
  int wm = (wid >> 1) * 64, wn = (wid & 1) * 64;                               \
  int arow = lane >> 2, acol = (lane & 3) * 8;                                 \
  const u16* gA0 = A_  + (size_t)(m0_ + wid * 32 + arow) * 512 + acol;         \
  const u16* gA1 = gA0 + (size_t)16 * 512;                                     \
  const u16* gB0 = Bt_ + (size_t)(n0_ + wid * 32 + arow) * 512 + acol;         \
  const u16* gB1 = gB0 + (size_t)16 * 512;                                     \
  f32x4 acc[4][4] = {};                                                        \
  G_STAGE(0, 0);                                                               \
  for (int it = 0; it < 4; it++) {                                             \
    G_STEP(0, 2 * it);                                                         \
    G_STEP(1, 2 * it + 1);                                                     \
  }                                                                            \
  __syncthreads();

// QKV: A=n1 [8192][512], Bt=wqkvT [1536][512]; scatter to Q/K [mh][s][d], Vt [mh][d][s]
__global__ __launch_bounds__(256) void k_gemm_qkv(
    const u16* __restrict__ A, const u16* __restrict__ Bt,
    const float* __restrict__ bq, const float* __restrict__ bk, const float* __restrict__ bv,
    u16* __restrict__ Qb, u16* __restrict__ Kb, u16* __restrict__ Vtb) {
  int m0 = blockIdx.y * 128, n0 = blockIdx.x * 128;
  GEMM_CORE(A, Bt, m0, n0)
  #pragma unroll
  for (int j = 0; j < 4; j++) {
    int n = n0 + wn + j * 16 + ln15;          // uniform t within 16-lane group
    int t = n >> 9, cc = n & 511, head = cc >> 6, dd = cc & 63;
    float bias = (t == 0) ? bq[cc] : ((t == 1) ? bk[cc] : bv[cc]);
    #pragma unroll
    for (int i = 0; i < 4; i++) {
      int row0 = m0 + wm + i * 16 + quad * 4;
      int mm = row0 >> 11, ss0 = row0 & 2047;
      if (t == 2) {
        union { u16 h[4]; u32x2 v; } pk;
        #pragma unroll
        for (int r = 0; r < 4; r++) pk.h[r] = f2bf(acc[i][j][r] + bias);
        *(u32x2*)(Vtb + ((size_t)(mm * 8 + head) * 64 + dd) * 2048 + ss0) = pk.v;
      } else {
        u16* dst = (t == 0) ? Qb : Kb;
        #pragma unroll
        for (int r = 0; r < 4; r++)
          dst[((size_t)(mm * 8 + head) * 2048 + ss0 + r) * 64 + dd] =
              f2bf(acc[i][j][r] + bias);
      }
    }
  }
}

// FFN1: A=n2 [8192][512], Bt=w1T [2048][512]; spike/candidate lists only
__global__ __launch_bounds__(256) void k_gemm_ffn1(
    const u16* __restrict__ A, const u16* __restrict__ Bt, const float* __restrict__ b1,
    int* __restrict__ cnt, unsigned* __restrict__ spikeL, unsigned* __restrict__ candL) {
  int m0 = blockIdx.y * 128, n0 = blockIdx.x * 128;
  GEMM_CORE(A, Bt, m0, n0)
  #pragma unroll
  for (int j = 0; j < 4; j++) {
    int n = n0 + wn + j * 16 + ln15;
    float bias = b1[n];
    #pragma unroll
    for (int i = 0; i < 4; i++) {
      #pragma unroll
      for (int r = 0; r < 4; r++) {
        int row = m0 + wm + i * 16 + quad * 4 + r;
        float hv = acc[i][j][r] + bias;
        if (hv >= 2.0f - MARGIN) {
          if (hv >= 2.0f + MARGIN) {
            int ix = atomicAdd(&cnt[0], 1);
            if (ix < CAP) spikeL[ix] = (unsigned)(row * 2048 + n);
          } else {
            int ix = atomicAdd(&cnt[1], 1);
            if (ix < CAP) candL[ix] = (unsigned)(row * 2048 + n);
          }
        }
      }
    }
  }
}

// ------- flash v7: v6 + bf16 att output -------
#define F_STAGE(BUF, T0)                                                       \
  do {                                                                         \
    gld16(gK0 + (size_t)(T0)       * 4096, &L.SB[BUF][0][0][rb0 * 64]);        \
    gld16(gK1 + (size_t)(T0)       * 4096, &L.SB[BUF][0][0][rb1 * 64]);        \
    gld16(gK0 + (size_t)((T0) + 1) * 4096, &L.SB[BUF][0][1][rb0 * 64]);        \
    gld16(gK1 + (size_t)((T0) + 1) * 4096, &L.SB[BUF][0][1][rb1 * 64]);        \
    gld16(gV0 + (T0) * 64,       &L.SB[BUF][1][0][rb0 * 64]);                  \
    gld16(gV1 + (T0) * 64,       &L.SB[BUF][1][0][rb1 * 64]);                  \
    gld16(gV0 + ((T0) + 1) * 64, &L.SB[BUF][1][1][rb0 * 64]);                  \
    gld16(gV1 + ((T0) + 1) * 64, &L.SB[BUF][1][1][rb1 * 64]);                  \
  } while (0)

#define F_INNER(BUF, SUB)                                                      \
  do {                                                                         \
    const u16* Kc = L.SB[BUF][0][SUB];                                         \
    const u16* Vc = L.SB[BUF][1][SUB];                                         \
    f32x4 s4[2][4];                                                            \
    _Pragma("unroll")                                                          \
    for (int j = 0; j < 4; j++) {                                              \
      bf16x8 a = *(const bf16x8*)(Kc + (j * 16 + ln15) * 64 + ((quad ^ lm) * 8)); \
      s4[0][j] = __builtin_amdgcn_mfma_f32_16x16x32_bf16(a, aQ[0][0].v, z4, 0, 0, 0); \
      s4[1][j] = __builtin_amdgcn_mfma_f32_16x16x32_bf16(a, aQ[1][0].v, z4, 0, 0, 0); \
    }                                                                          \
    _Pragma("unroll")                                                          \
    for (int j = 0; j < 4; j++) {                                              \
      bf16x8 a = *(const bf16x8*)(Kc + (j * 16 + ln15) * 64 + (((4 + quad) ^ lm) * 8)); \
      s4[0][j] = __builtin_amdgcn_mfma_f32_16x16x32_bf16(a, aQ[0][1].v, s4[0][j], 0, 0, 0); \
      s4[1][j] = __builtin_amdgcn_mfma_f32_16x16x32_bf16(a, aQ[1][1].v, s4[1][j], 0, 0, 0); \
    }                                                                          \
    Frag4 bP[2][2];                                                            \
    _Pragma("unroll")                                                          \
    for (int h = 0; h < 2; h++) {                                              \
      unsigned pr[4][4];                                                       \
      _Pragma("unroll")                                                        \
      for (int j = 0; j < 4; j++)                                              \
        _Pragma("unroll")                                                      \
        for (int r = 0; r < 4; r++) {                                          \
          float p = __builtin_amdgcn_exp2f(fmaf(s4[h][j][r], LOG2E, EXPB));    \
          l[h] += p;                                                           \
          union { float f; unsigned u; } cc; cc.f = p;                         \
          pr[j][r] = cc.u;                                                     \
        }                                                                      \
      _Pragma("unroll")                                                        \
      for (int t = 0; t < 2; t++) {                                            \
        bP[h][t].u[0] = __builtin_amdgcn_perm(pr[2*t][1],   pr[2*t][0],   0x07060302u); \
        bP[h][t].u[1] = __builtin_amdgcn_perm(pr[2*t][3],   pr[2*t][2],   0x07060302u); \
        bP[h][t].u[2] = __builtin_amdgcn_perm(pr[2*t+1][1], pr[2*t+1][0], 0x07060302u); \
        bP[h][t].u[3] = __builtin_amdgcn_perm(pr[2*t+1][3], pr[2*t+1][2], 0x07060302u); \
      }                                                                        \
    }                                                                          \
    _Pragma("unroll")                                                          \
    for (int t = 0; t < 2; t++)                                                \
      _Pragma("unroll")                                                        \
      for (int j = 0; j < 4; j++) {                                            \
        int row = j * 16 + ln15;                                               \
        int c0 = 4 * t + (quad >> 1), sub = (quad & 1) * 4;                    \
        Frag aV;                                                               \
        aV.u[0] = *(const u32x2*)(Vc + row * 64 + ((c0 ^ lm) * 8) + sub);      \
        aV.u[1] = *(const u32x2*)(Vc + row * 64 + (((c0 + 2) ^ lm) * 8) + sub);\
        U[0][j] = __builtin_amdgcn_mfma_f32_16x16x32_bf16(aV.v, bP[0][t].v,    \
                                                          U[0][j], 0, 0, 0);   \
        U[1][j] = __builtin_amdgcn_mfma_f32_16x16x32_bf16(aV.v, bP[1][t].v,    \
                                                          U[1][j], 0, 0, 0);   \
      }                                                                        \
  } while (0)

#define F_STEP(CUR, S)                                                         \
  do {                                                                         \
    __syncthreads();                                                           \
    if ((S) < 15) F_STAGE((CUR) ^ 1, 2 * (S) + 2);                             \
    F_INNER(CUR, 0);                                                           \
    F_INNER(CUR, 1);                                                           \
  } while (0)

__global__ __launch_bounds__(256, 2) void k_flash(
    const u16* __restrict__ Q, const u16* __restrict__ K,
    const u16* __restrict__ Vt, u16* __restrict__ att) {
  __shared__ union {
    u16 SB[2][2][2][64 * 64];  // [buf][K/V][sub][64 rows][64 u16 chunk-swizzled] 64 KB
    float T[4][16 * 68];       // per-wave epilogue transpose (after final barrier)
  } L;
  int tid = threadIdx.x, wid = tid >> 6, lane = tid & 63;
  int quad = lane >> 4, ln15 = lane & 15, lm = ln15 & 7;
  int qb = blockIdx.x, head = blockIdx.y, mm = blockIdx.z;
  int mh = mm * 8 + head;
  const u16* Qp = Q  + (size_t)mh * SEQ * HD;
  const u16* Kp = K  + (size_t)mh * SEQ * HD;
  const u16* Vp = Vt + (size_t)mh * HD * SEQ;
  int q0 = qb * 128 + wid * 32;

  Frag aQ[2][2];   // [q-half][t]: B-operand Q[q=ln15][d=t*32+quad*8+..]
  #pragma unroll
  for (int h = 0; h < 2; h++)
    #pragma unroll
    for (int t = 0; t < 2; t++) {
      u32x4 g = *(const u32x4*)(Qp + (size_t)(q0 + h * 16 + ln15) * 64 + t * 32 + quad * 8);
      aQ[h][t].u[0].x = g.x; aQ[h][t].u[0].y = g.y;
      aQ[h][t].u[1].x = g.z; aQ[h][t].u[1].y = g.w;
    }
  const f32x4 z4 = {0.f, 0.f, 0.f, 0.f};

  // staging: lane -> (row l>>3, phys chunk l&7) holds global chunk (l&7)^(l>>3&7)
  int srow = lane >> 3;
  int sch  = (lane & 7) ^ (srow & 7);
  int rb0 = wid * 16, rb1 = wid * 16 + 8;
  const u16* gK0 = Kp + (size_t)(rb0 + srow) * 64 + sch * 8;
  const u16* gK1 = Kp + (size_t)(rb1 + srow) * 64 + sch * 8;
  const u16* gV0 = Vp + (size_t)(rb0 + srow) * SEQ + sch * 8;
  const u16* gV1 = Vp + (size_t)(rb1 + srow) * SEQ + sch * 8;

  float l[2] = {0.f, 0.f};
  f32x4 U[2][4] = {};          // [q-half][j]: U^T[d=j*16+quad*4+r][q=ln15]

  F_STAGE(0, 0);
  for (int it = 0; it < 8; it++) {
    F_STEP(0, 2 * it);
    F_STEP(1, 2 * it + 1);
  }
  __syncthreads();   // protect T-union from other waves' last-step LDS reads

  #pragma unroll
  for (int h = 0; h < 2; h++) {
    float lv = l[h];
    lv += __shfl_xor(lv, 16);
    lv += __shfl_xor(lv, 32);
    float rl = 1.0f / lv;
    float* Tw = L.T[wid];
    #pragma unroll
    for (int j = 0; j < 4; j++)
      *(f32x4*)(Tw + ln15 * 68 + j * 16 + quad * 4) = U[h][j] * rl;
    #pragma unroll
    for (int s = 0; s < 4; s++) {
      f32x4 o = *(const f32x4*)(Tw + (quad * 4 + s) * 68 + ln15 * 4);
      union { u16 h4[4]; u32x2 v; } pk;
      pk.h4[0] = f2bf(o.x); pk.h4[1] = f2bf(o.y);
      pk.h4[2] = f2bf(o.z); pk.h4[3] = f2bf(o.w);
      *(u32x2*)(att + ((size_t)mm * SEQ + q0 + h * 16 + quad * 4 + s) * EMB +
                head * 64 + ln15 * 4) = pk.v;
    }
  }
}

// exact fp32 recompute of borderline h1 entries; append true spikes
__global__ __launch_bounds__(256) void k_fixup(
    const float* __restrict__ x2, const float* __restrict__ w1, const float* __restrict__ b1,
    const float* __restrict__ g2, const float* __restrict__ be2,
    int* __restrict__ cnt, unsigned* __restrict__ spikeL, const unsigned* __restrict__ candL) {
  __shared__ float sb[8];
  int tid = threadIdx.x;
  int nC = cnt[1]; if (nC > CAP) nC = CAP;
  for (int e = blockIdx.x; e < nC; e += gridDim.x) {
    unsigned v = candL[e];
    int row = (int)(v >> 11), col = (int)(v & 2047u);
    const float* xr = x2 + (size_t)row * 512;
    float x0 = xr[tid], x1 = xr[tid + 256];
    float s = x0 + x1, q = x0 * x0 + x1 * x1;
    #pragma unroll
    for (int o = 1; o < 64; o <<= 1) { s += __shfl_xor(s, o); q += __shfl_xor(q, o); }
    if ((tid & 63) == 0) { sb[tid >> 6] = s; sb[4 + (tid >> 6)] = q; }
    __syncthreads();
    float st = sb[0] + sb[1] + sb[2] + sb[3];
    float qt = sb[4] + sb[5] + sb[6] + sb[7];
    __syncthreads();
    float mu = st * (1.f / 512.f);
    float rs = 1.f / sqrtf(qt * (1.f / 512.f) - mu * mu + 1e-5f);
    float na = (x0 - mu) * rs * g2[tid] + be2[tid];
    float nb = (x1 - mu) * rs * g2[tid + 256] + be2[tid + 256];
    float dd = na * w1[(size_t)tid * 2048 + col] + nb * w1[(size_t)(tid + 256) * 2048 + col];
    #pragma unroll
    for (int o = 1; o < 64; o <<= 1) dd += __shfl_xor(dd, o);
    if ((tid & 63) == 0) sb[tid >> 6] = dd;
    __syncthreads();
    if (tid == 0) {
      float hv = sb[0] + sb[1] + sb[2] + sb[3] + b1[col];
      if (hv >= 2.0f) { int ix = atomicAdd(&cnt[0], 1); if (ix < CAP) spikeL[ix] = v; }
    }
    __syncthreads();
  }
}

// out[row,:] += w2[col,:] for each spike
__global__ void k_apply(const float* __restrict__ w2, const int* __restrict__ cnt,
                        const unsigned* __restrict__ spikeL, float* __restrict__ out) {
  int n = cnt[0]; if (n > CAP) n = CAP;
  int tid = threadIdx.x;
  for (int e = blockIdx.x; e < n; e += gridDim.x) {
    unsigned v = spikeL[e];
    int row = (int)(v >> 11), col = (int)(v & 2047u);
    atomicAdd(&out[(size_t)row * 512 + tid * 2 + 0], w2[(size_t)col * 512 + tid * 2 + 0]);
    atomicAdd(&out[(size_t)row * 512 + tid * 2 + 1], w2[(size_t)col * 512 + tid * 2 + 1]);
  }
}

// ---------------- launch ----------------

extern "C" void kernel_launch(void* const* d_in, const int* in_sizes, int n_in,
                              void* d_out, int out_size, void* d_ws, size_t ws_size,
                              hipStream_t stream) {
  (void)in_sizes; (void)n_in; (void)out_size; (void)ws_size;
  const float* x   = (const float*)d_in[0];
  const float* wq  = (const float*)d_in[1];
  const float* bq  = (const float*)d_in[2];
  const float* wk  = (const float*)d_in[3];
  const float* bk  = (const float*)d_in[4];
  const float* wv  = (const float*)d_in[5];
  const float* bv  = (const float*)d_in[6];
  const float* w1  = (const float*)d_in[7];
  const float* b1  = (const float*)d_in[8];
  const float* w2  = (const float*)d_in[9];
  const float* b2  = (const float*)d_in[10];
  const float* g1  = (const float*)d_in[11];
  const float* be1 = (const float*)d_in[12];
  const float* g2  = (const float*)d_in[13];
  const float* be2 = (const float*)d_in[14];
  float* out = (float*)d_out;

  char* w = (char*)d_ws;
  size_t off = 0;
  auto take = [&](size_t bytes) { char* p = w + off; off += (bytes + 255) & ~(size_t)255; return p; };
  int*      cnt    = (int*)take(256);
  u16*      n1     = (u16*)take((size_t)ROWS * EMB * 2);
  u16*      wqkvT  = (u16*)take((size_t)1536 * 512 * 2);
  u16*      w1T    = (u16*)take((size_t)2048 * 512 * 2);
  u16*      Qb     = (u16*)take((size_t)MB * NH * SEQ * HD * 2);
  u16*      Kb     = (u16*)take((size_t)MB * NH * SEQ * HD * 2);
  u16*      Vtb    = (u16*)take((size_t)MB * NH * SEQ * HD * 2);
  u16*      att    = (u16*)take((size_t)ROWS * EMB * 2);
  float*    x2     = (float*)take((size_t)ROWS * EMB * 4);
  u16*      n2     = (u16*)take((size_t)ROWS * EMB * 2);
  unsigned* spikeL = (unsigned*)take((size_t)CAP * 4);
  unsigned* candL  = (unsigned*)take((size_t)CAP * 4);

  k_prep<<<3840, 256, 0, stream>>>(x, g1, be1, wq, wk, wv, w1, n1, wqkvT, w1T, cnt);
  k_gemm_qkv<<<dim3(12, 64), 256, 0, stream>>>(n1, wqkvT, bq, bk, bv, Qb, Kb, Vtb);
  k_flash<<<dim3(16, 8, 4), 256, 0, stream>>>(Qb, Kb, Vtb, att);
  k_ln2<<<ROWS / 4, 256, 0, stream>>>(x, att, g2, be2, b2, x2, n2, out);
  k_gemm_ffn1<<<dim3(16, 64), 256, 0, stream>>>(n2, w1T, b1, cnt, spikeL, candL);
  k_fixup<<<256, 256, 0, stream>>>(x2, w1, b1, g2, be2, cnt, spikeL, candL);
  k_apply<<<128, 256, 0, stream>>>(w2, cnt, spikeL, out);
}

// Round 9
// 204.494 us; speedup vs baseline: 1.0574x; 1.0574x over previous
//
#include <hip/hip_runtime.h>
#include <stdint.h>

#define EMB 512
#define SEQ 2048
#define MB 4
#define NH 8
#define HD 64
#define ROWS (MB*SEQ)          // 8192
#define MARGIN 0.02f
#define CAP 65536
#define LOG2E 1.44269504f
#define EXPB (-17.3123405f)    // -12 * log2(e)

typedef unsigned short u16;
typedef __attribute__((ext_vector_type(8))) short bf16x8;   // 8 bf16 (4 VGPRs)
typedef __attribute__((ext_vector_type(4))) float f32x4;
typedef __attribute__((ext_vector_type(2))) unsigned int u32x2;
typedef __attribute__((ext_vector_type(4))) unsigned int u32x4;

union Frag { u32x2 u[2]; bf16x8 v; };
union Frag4 { unsigned u[4]; bf16x8 v; };

__device__ __forceinline__ u16 f2bf(float f) {
  union { float f; unsigned u; } a; a.f = f;
  unsigned r = a.u + 0x7FFFu + ((a.u >> 16) & 1u);  // RNE
  return (u16)(r >> 16);
}
__device__ __forceinline__ float bflo(unsigned u) {
  union { unsigned u; float f; } c; c.u = u << 16; return c.f;
}
__device__ __forceinline__ float bfhi(unsigned u) {
  union { unsigned u; float f; } c; c.u = u & 0xffff0000u; return c.f;
}
// async global->LDS, 16B per lane; LDS dest = wave-uniform base + lane*16
__device__ __forceinline__ void gld16(const void* g, void* l) {
  __builtin_amdgcn_global_load_lds(
      (const __attribute__((address_space(1))) void*)g,
      (__attribute__((address_space(3))) void*)l, 16, 0, 0);
}

// ---------------- fused prep: 4 weight transposes (blocks 0..1791) + LN1 (1792..3839) ----

__global__ __launch_bounds__(256) void k_prep(
    const float* __restrict__ x, const float* __restrict__ g1, const float* __restrict__ be1,
    const float* __restrict__ wq, const float* __restrict__ wk,
    const float* __restrict__ wv, const float* __restrict__ w1,
    u16* __restrict__ n1, u16* __restrict__ wqkvT, u16* __restrict__ w1T,
    int* __restrict__ cnt) {
  __shared__ float tile[32][33];
  int b = blockIdx.x, tid = threadIdx.x;
  if (b < 1792) {
    const float* src; u16* dst; int N, bx, by;
    if (b < 768) {
      int z = b >> 8, rem = b & 255; bx = rem & 15; by = rem >> 4; N = 512;
      src = (z == 0) ? wq : ((z == 1) ? wk : wv);
      dst = wqkvT + z * 512 * 512;
    } else {
      int rem = b - 768; bx = rem & 63; by = rem >> 6; N = 2048;
      src = w1; dst = w1T;
    }
    int tx = tid & 31, ty = tid >> 5;
    int k0 = by * 32, n0 = bx * 32;
    for (int i = 0; i < 32; i += 8)
      tile[ty + i][tx] = src[(size_t)(k0 + ty + i) * N + n0 + tx];
    __syncthreads();
    for (int i = 0; i < 32; i += 8)
      dst[(size_t)(n0 + ty + i) * 512 + k0 + tx] = f2bf(tile[tx][ty + i]);
  } else {
    if (b == 1792 && tid < 2) cnt[tid] = 0;
    int wid = tid >> 6, lane = tid & 63;
    int row = (b - 1792) * 4 + wid;
    const float* xr = x + (size_t)row * EMB + lane * 8;
    f32x4 v0 = *(const f32x4*)xr;
    f32x4 v1 = *(const f32x4*)(xr + 4);
    float s = v0.x+v0.y+v0.z+v0.w + v1.x+v1.y+v1.z+v1.w;
    float q = v0.x*v0.x+v0.y*v0.y+v0.z*v0.z+v0.w*v0.w
            + v1.x*v1.x+v1.y*v1.y+v1.z*v1.z+v1.w*v1.w;
    #pragma unroll
    for (int o = 1; o < 64; o <<= 1) { s += __shfl_xor(s, o); q += __shfl_xor(q, o); }
    float mu = s * (1.0f/512.0f);
    float rs = 1.0f / sqrtf(q * (1.0f/512.0f) - mu*mu + 1e-5f);
    f32x4 ga = *(const f32x4*)(g1 + lane*8), gb = *(const f32x4*)(g1 + lane*8 + 4);
    f32x4 ba = *(const f32x4*)(be1 + lane*8), bb = *(const f32x4*)(be1 + lane*8 + 4);
    union { u16 h[8]; u32x4 v; } o8;
    o8.h[0] = f2bf((v0.x-mu)*rs*ga.x + ba.x); o8.h[1] = f2bf((v0.y-mu)*rs*ga.y + ba.y);
    o8.h[2] = f2bf((v0.z-mu)*rs*ga.z + ba.z); o8.h[3] = f2bf((v0.w-mu)*rs*ga.w + ba.w);
    o8.h[4] = f2bf((v1.x-mu)*rs*gb.x + bb.x); o8.h[5] = f2bf((v1.y-mu)*rs*gb.y + bb.y);
    o8.h[6] = f2bf((v1.z-mu)*rs*gb.z + bb.z); o8.h[7] = f2bf((v1.w-mu)*rs*gb.w + bb.w);
    *(u32x4*)(n1 + (size_t)row * EMB + lane * 8) = o8.v;
  }
}

// x2 = x + att(bf16) ; n2 = LN(x2) ; out = x2 + b2
__global__ __launch_bounds__(256) void k_ln2(const float* __restrict__ x,
    const u16* __restrict__ att, const float* __restrict__ g, const float* __restrict__ b,
    const float* __restrict__ b2, float* __restrict__ x2, u16* __restrict__ n2,
    float* __restrict__ out) {
  int wid = threadIdx.x >> 6, lane = threadIdx.x & 63;
  int row = blockIdx.x * 4 + wid;
  size_t base = (size_t)row * EMB + lane * 8;
  u32x4 av = *(const u32x4*)(att + base);
  f32x4 t0, t1;
  t0.x = bflo(av.x); t0.y = bfhi(av.x); t0.z = bflo(av.y); t0.w = bfhi(av.y);
  t1.x = bflo(av.z); t1.y = bfhi(av.z); t1.z = bflo(av.w); t1.w = bfhi(av.w);
  f32x4 v0 = *(const f32x4*)(x + base)     + t0;
  f32x4 v1 = *(const f32x4*)(x + base + 4) + t1;
  *(f32x4*)(x2 + base) = v0;
  *(f32x4*)(x2 + base + 4) = v1;
  *(f32x4*)(out + base)     = v0 + *(const f32x4*)(b2 + lane*8);
  *(f32x4*)(out + base + 4) = v1 + *(const f32x4*)(b2 + lane*8 + 4);
  float s = v0.x+v0.y+v0.z+v0.w + v1.x+v1.y+v1.z+v1.w;
  float q = v0.x*v0.x+v0.y*v0.y+v0.z*v0.z+v0.w*v0.w
          + v1.x*v1.x+v1.y*v1.y+v1.z*v1.z+v1.w*v1.w;
  #pragma unroll
  for (int o = 1; o < 64; o <<= 1) { s += __shfl_xor(s, o); q += __shfl_xor(q, o); }
  float mu = s * (1.0f/512.0f);
  float rs = 1.0f / sqrtf(q * (1.0f/512.0f) - mu*mu + 1e-5f);
  f32x4 ga = *(const f32x4*)(g + lane*8), gb = *(const f32x4*)(g + lane*8 + 4);
  f32x4 ba = *(const f32x4*)(b + lane*8), bb = *(const f32x4*)(b + lane*8 + 4);
  union { u16 h[8]; u32x4 v; } o8;
  o8.h[0] = f2bf((v0.x-mu)*rs*ga.x + ba.x); o8.h[1] = f2bf((v0.y-mu)*rs*ga.y + ba.y);
  o8.h[2] = f2bf((v0.z-mu)*rs*ga.z + ba.z); o8.h[3] = f2bf((v0.w-mu)*rs*ga.w + ba.w);
  o8.h[4] = f2bf((v1.x-mu)*rs*gb.x + bb.x); o8.h[5] = f2bf((v1.y-mu)*rs*gb.y + bb.y);
  o8.h[6] = f2bf((v1.z-mu)*rs*gb.z + bb.z); o8.h[7] = f2bf((v1.w-mu)*rs*gb.w + bb.w);
  *(u32x4*)(n2 + (size_t)row * EMB + lane * 8) = o8.v;
}

// -------- GEMM core (r6-proven, reverted from r8's 64KB variant): 32KB dbuf, --------
// 1 barrier/tile, ~5 blocks/CU. r8's 2-tiles/barrier halved occupancy (64KB LDS
// -> 2 blocks/CU) and regressed +5us: barrier-halving only pays when LDS isn't
// the occupancy limiter.
#define GEMM_CORE(A_, Bt_, m0_, n0_)                                           \
  __shared__ u16 As[2][128 * 32];                                              \
  __shared__ u16 Bs[2][128 * 32];                                              \
  int tid = threadIdx.x;                                                       \
  int wid = tid >> 6, lane = tid & 63;                                         \
  int quad = lane >> 4, ln15 = lane & 15;                                      \
  int wm = (wid >> 1) * 64, wn = (wid & 1) * 64;                               \
  int arow = lane >> 2, acol = (lane & 3) * 8;                                 \
  const u16* gA0 = A_  + (size_t)(m0_ + wid * 32 + arow) * 512 + acol;         \
  const u16* gA1 = gA0 + (size_t)16 * 512;                                     \
  const u16* gB0 = Bt_ + (size_t)(n0_ + wid * 32 + arow) * 512 + acol;         \
  const u16* gB1 = gB0 + (size_t)16 * 512;                                     \
  f32x4 acc[4][4] = {};                                                        \
  gld16(gA0, &As[0][(wid * 32) * 32]); gld16(gA1, &As[0][(wid * 32 + 16) * 32]);\
  gld16(gB0, &Bs[0][(wid * 32) * 32]); gld16(gB1, &Bs[0][(wid * 32 + 16) * 32]);\
  for (int kt = 0; kt < 16; kt++) {                                            \
    int cur = kt & 1;                                                          \
    __syncthreads();                                                           \
    if (kt < 15) {                                                             \
      int ko = (kt + 1) * 32;                                                  \
      gld16(gA0 + ko, &As[cur ^ 1][(wid * 32) * 32]);                          \
      gld16(gA1 + ko, &As[cur ^ 1][(wid * 32 + 16) * 32]);                     \
      gld16(gB0 + ko, &Bs[cur ^ 1][(wid * 32) * 32]);                          \
      gld16(gB1 + ko, &Bs[cur ^ 1][(wid * 32 + 16) * 32]);                     \
    }                                                                          \
    bf16x8 af[4], bf[4];                                                       \
    _Pragma("unroll")                                                          \
    for (int i = 0; i < 4; i++) {                                              \
      af[i] = *(const bf16x8*)&As[cur][(wm + i * 16 + ln15) * 32 + quad * 8];  \
      bf[i] = *(const bf16x8*)&Bs[cur][(wn + i * 16 + ln15) * 32 + quad * 8];  \
    }                                                                          \
    _Pragma("unroll")                                                          \
    for (int i = 0; i < 4; i++)                                                \
      _Pragma("unroll")                                                        \
      for (int j = 0; j < 4; j++)                                              \
        acc[i][j] = __builtin_amdgcn_mfma_f32_16x16x32_bf16(af[i], bf[j],      \
                                                            acc[i][j], 0, 0, 0);\
  }                                                                            \
  __syncthreads();

// QKV: A=n1 [8192][512], Bt=wqkvT [1536][512]; scatter to Q/K [mh][s][d], Vt [mh][d][s]
__global__ __launch_bounds__(256) void k_gemm_qkv(
    const u16* __restrict__ A, const u16* __restrict__ Bt,
    const float* __restrict__ bq, const float* __restrict__ bk, const float* __restrict__ bv,
    u16* __restrict__ Qb, u16* __restrict__ Kb, u16* __restrict__ Vtb) {
  int m0 = blockIdx.y * 128, n0 = blockIdx.x * 128;
  GEMM_CORE(A, Bt, m0, n0)
  #pragma unroll
  for (int j = 0; j < 4; j++) {
    int n = n0 + wn + j * 16 + ln15;          // uniform t within 16-lane group
    int t = n >> 9, cc = n & 511, head = cc >> 6, dd = cc & 63;
    float bias = (t == 0) ? bq[cc] : ((t == 1) ? bk[cc] : bv[cc]);
    #pragma unroll
    for (int i = 0; i < 4; i++) {
      int row0 = m0 + wm + i * 16 + quad * 4;
      int mm = row0 >> 11, ss0 = row0 & 2047;
      if (t == 2) {
        union { u16 h[4]; u32x2 v; } pk;
        #pragma unroll
        for (int r = 0; r < 4; r++) pk.h[r] = f2bf(acc[i][j][r] + bias);
        *(u32x2*)(Vtb + ((size_t)(mm * 8 + head) * 64 + dd) * 2048 + ss0) = pk.v;
      } else {
        u16* dst = (t == 0) ? Qb : Kb;
        #pragma unroll
        for (int r = 0; r < 4; r++)
          dst[((size_t)(mm * 8 + head) * 2048 + ss0 + r) * 64 + dd] =
              f2bf(acc[i][j][r] + bias);
      }
    }
  }
}

// FFN1: A=n2 [8192][512], Bt=w1T [2048][512]; spike/candidate lists only
__global__ __launch_bounds__(256) void k_gemm_ffn1(
    const u16* __restrict__ A, const u16* __restrict__ Bt, const float* __restrict__ b1,
    int* __restrict__ cnt, unsigned* __restrict__ spikeL, unsigned* __restrict__ candL) {
  int m0 = blockIdx.y * 128, n0 = blockIdx.x * 128;
  GEMM_CORE(A, Bt, m0, n0)
  #pragma unroll
  for (int j = 0; j < 4; j++) {
    int n = n0 + wn + j * 16 + ln15;
    float bias = b1[n];
    #pragma unroll
    for (int i = 0; i < 4; i++) {
      #pragma unroll
      for (int r = 0; r < 4; r++) {
        int row = m0 + wm + i * 16 + quad * 4 + r;
        float hv = acc[i][j][r] + bias;
        if (hv >= 2.0f - MARGIN) {
          if (hv >= 2.0f + MARGIN) {
            int ix = atomicAdd(&cnt[0], 1);
            if (ix < CAP) spikeL[ix] = (unsigned)(row * 2048 + n);
          } else {
            int ix = atomicAdd(&cnt[1], 1);
            if (ix < CAP) candL[ix] = (unsigned)(row * 2048 + n);
          }
        }
      }
    }
  }
}

// ------- flash v7 (r8-proven): 128 K-rows/barrier, zero-C QK, bf16 att output -------
#define F_STAGE(BUF, T0)                                                       \
  do {                                                                         \
    gld16(gK0 + (size_t)(T0)       * 4096, &L.SB[BUF][0][0][rb0 * 64]);        \
    gld16(gK1 + (size_t)(T0)       * 4096, &L.SB[BUF][0][0][rb1 * 64]);        \
    gld16(gK0 + (size_t)((T0) + 1) * 4096, &L.SB[BUF][0][1][rb0 * 64]);        \
    gld16(gK1 + (size_t)((T0) + 1) * 4096, &L.SB[BUF][0][1][rb1 * 64]);        \
    gld16(gV0 + (T0) * 64,       &L.SB[BUF][1][0][rb0 * 64]);                  \
    gld16(gV1 + (T0) * 64,       &L.SB[BUF][1][0][rb1 * 64]);                  \
    gld16(gV0 + ((T0) + 1) * 64, &L.SB[BUF][1][1][rb0 * 64]);                  \
    gld16(gV1 + ((T0) + 1) * 64, &L.SB[BUF][1][1][rb1 * 64]);                  \
  } while (0)

#define F_INNER(BUF, SUB)                                                      \
  do {                                                                         \
    const u16* Kc = L.SB[BUF][0][SUB];                                         \
    const u16* Vc = L.SB[BUF][1][SUB];                                         \
    f32x4 s4[2][4];                                                            \
    _Pragma("unroll")                                                          \
    for (int j = 0; j < 4; j++) {                                              \
      bf16x8 a = *(const bf16x8*)(Kc + (j * 16 + ln15) * 64 + ((quad ^ lm) * 8)); \
      s4[0][j] = __builtin_amdgcn_mfma_f32_16x16x32_bf16(a, aQ[0][0].v, z4, 0, 0, 0); \
      s4[1][j] = __builtin_amdgcn_mfma_f32_16x16x32_bf16(a, aQ[1][0].v, z4, 0, 0, 0); \
    }                                                                          \
    _Pragma("unroll")                                                          \
    for (int j = 0; j < 4; j++) {                                              \
      bf16x8 a = *(const bf16x8*)(Kc + (j * 16 + ln15) * 64 + (((4 + quad) ^ lm) * 8)); \
      s4[0][j] = __builtin_amdgcn_mfma_f32_16x16x32_bf16(a, aQ[0][1].v, s4[0][j], 0, 0, 0); \
      s4[1][j] = __builtin_amdgcn_mfma_f32_16x16x32_bf16(a, aQ[1][1].v, s4[1][j], 0, 0, 0); \
    }                                                                          \
    Frag4 bP[2][2];                                                            \
    _Pragma("unroll")                                                          \
    for (int h = 0; h < 2; h++) {                                              \
      unsigned pr[4][4];                                                       \
      _Pragma("unroll")                                                        \
      for (int j = 0; j < 4; j++)                                              \
        _Pragma("unroll")                                                      \
        for (int r = 0; r < 4; r++) {                                          \
          float p = __builtin_amdgcn_exp2f(fmaf(s4[h][j][r], LOG2E, EXPB));    \
          l[h] += p;                                                           \
          union { float f; unsigned u; } cc; cc.f = p;                         \
          pr[j][r] = cc.u;                                                     \
        }                                                                      \
      _Pragma("unroll")                                                        \
      for (int t = 0; t < 2; t++) {                                            \
        bP[h][t].u[0] = __builtin_amdgcn_perm(pr[2*t][1],   pr[2*t][0],   0x07060302u); \
        bP[h][t].u[1] = __builtin_amdgcn_perm(pr[2*t][3],   pr[2*t][2],   0x07060302u); \
        bP[h][t].u[2] = __builtin_amdgcn_perm(pr[2*t+1][1], pr[2*t+1][0], 0x07060302u); \
        bP[h][t].u[3] = __builtin_amdgcn_perm(pr[2*t+1][3], pr[2*t+1][2], 0x07060302u); \
      }                                                                        \
    }                                                                          \
    _Pragma("unroll")                                                          \
    for (int t = 0; t < 2; t++)                                                \
      _Pragma("unroll")                                                        \
      for (int j = 0; j < 4; j++) {                                            \
        int row = j * 16 + ln15;                                               \
        int c0 = 4 * t + (quad >> 1), sub = (quad & 1) * 4;                    \
        Frag aV;                                                               \
        aV.u[0] = *(const u32x2*)(Vc + row * 64 + ((c0 ^ lm) * 8) + sub);      \
        aV.u[1] = *(const u32x2*)(Vc + row * 64 + (((c0 + 2) ^ lm) * 8) + sub);\
        U[0][j] = __builtin_amdgcn_mfma_f32_16x16x32_bf16(aV.v, bP[0][t].v,    \
                                                          U[0][j], 0, 0, 0);   \
        U[1][j] = __builtin_amdgcn_mfma_f32_16x16x32_bf16(aV.v, bP[1][t].v,    \
                                                          U[1][j], 0, 0, 0);   \
      }                                                                        \
  } while (0)

#define F_STEP(CUR, S)                                                         \
  do {                                                                         \
    __syncthreads();                                                           \
    if ((S) < 15) F_STAGE((CUR) ^ 1, 2 * (S) + 2);                             \
    F_INNER(CUR, 0);                                                           \
    F_INNER(CUR, 1);                                                           \
  } while (0)

__global__ __launch_bounds__(256, 2) void k_flash(
    const u16* __restrict__ Q, const u16* __restrict__ K,
    const u16* __restrict__ Vt, u16* __restrict__ att) {
  __shared__ union {
    u16 SB[2][2][2][64 * 64];  // [buf][K/V][sub][64 rows][64 u16 chunk-swizzled] 64 KB
    float T[4][16 * 68];       // per-wave epilogue transpose (after final barrier)
  } L;
  int tid = threadIdx.x, wid = tid >> 6, lane = tid & 63;
  int quad = lane >> 4, ln15 = lane & 15, lm = ln15 & 7;
  int qb = blockIdx.x, head = blockIdx.y, mm = blockIdx.z;
  int mh = mm * 8 + head;
  const u16* Qp = Q  + (size_t)mh * SEQ * HD;
  const u16* Kp = K  + (size_t)mh * SEQ * HD;
  const u16* Vp = Vt + (size_t)mh * HD * SEQ;
  int q0 = qb * 128 + wid * 32;

  Frag aQ[2][2];   // [q-half][t]: B-operand Q[q=ln15][d=t*32+quad*8+..]
  #pragma unroll
  for (int h = 0; h < 2; h++)
    #pragma unroll
    for (int t = 0; t < 2; t++) {
      u32x4 g = *(const u32x4*)(Qp + (size_t)(q0 + h * 16 + ln15) * 64 + t * 32 + quad * 8);
      aQ[h][t].u[0].x = g.x; aQ[h][t].u[0].y = g.y;
      aQ[h][t].u[1].x = g.z; aQ[h][t].u[1].y = g.w;
    }
  const f32x4 z4 = {0.f, 0.f, 0.f, 0.f};

  // staging: lane -> (row l>>3, phys chunk l&7) holds global chunk (l&7)^(l>>3&7)
  int srow = lane >> 3;
  int sch  = (lane & 7) ^ (srow & 7);
  int rb0 = wid * 16, rb1 = wid * 16 + 8;
  const u16* gK0 = Kp + (size_t)(rb0 + srow) * 64 + sch * 8;
  const u16* gK1 = Kp + (size_t)(rb1 + srow) * 64 + sch * 8;
  const u16* gV0 = Vp + (size_t)(rb0 + srow) * SEQ + sch * 8;
  const u16* gV1 = Vp + (size_t)(rb1 + srow) * SEQ + sch * 8;

  float l[2] = {0.f, 0.f};
  f32x4 U[2][4] = {};          // [q-half][j]: U^T[d=j*16+quad*4+r][q=ln15]

  F_STAGE(0, 0);
  for (int it = 0; it < 8; it++) {
    F_STEP(0, 2 * it);
    F_STEP(1, 2 * it + 1);
  }
  __syncthreads();   // protect T-union from other waves' last-step LDS reads

  #pragma unroll
  for (int h = 0; h < 2; h++) {
    float lv = l[h];
    lv += __shfl_xor(lv, 16);
    lv += __shfl_xor(lv, 32);
    float rl = 1.0f / lv;
    float* Tw = L.T[wid];
    #pragma unroll
    for (int j = 0; j < 4; j++)
      *(f32x4*)(Tw + ln15 * 68 + j * 16 + quad * 4) = U[h][j] * rl;
    #pragma unroll
    for (int s = 0; s < 4; s++) {
      f32x4 o = *(const f32x4*)(Tw + (quad * 4 + s) * 68 + ln15 * 4);
      union { u16 h4[4]; u32x2 v; } pk;
      pk.h4[0] = f2bf(o.x); pk.h4[1] = f2bf(o.y);
      pk.h4[2] = f2bf(o.z); pk.h4[3] = f2bf(o.w);
      *(u32x2*)(att + ((size_t)mm * SEQ + q0 + h * 16 + quad * 4 + s) * EMB +
                head * 64 + ln15 * 4) = pk.v;
    }
  }
}

// exact fp32 recompute of borderline h1 entries; append true spikes
__global__ __launch_bounds__(256) void k_fixup(
    const float* __restrict__ x2, const float* __restrict__ w1, const float* __restrict__ b1,
    const float* __restrict__ g2, const float* __restrict__ be2,
    int* __restrict__ cnt, unsigned* __restrict__ spikeL, const unsigned* __restrict__ candL) {
  __shared__ float sb[8];
  int tid = threadIdx.x;
  int nC = cnt[1]; if (nC > CAP) nC = CAP;
  for (int e = blockIdx.x; e < nC; e += gridDim.x) {
    unsigned v = candL[e];
    int row = (int)(v >> 11), col = (int)(v & 2047u);
    const float* xr = x2 + (size_t)row * 512;
    float x0 = xr[tid], x1 = xr[tid + 256];
    float s = x0 + x1, q = x0 * x0 + x1 * x1;
    #pragma unroll
    for (int o = 1; o < 64; o <<= 1) { s += __shfl_xor(s, o); q += __shfl_xor(q, o); }
    if ((tid & 63) == 0) { sb[tid >> 6] = s; sb[4 + (tid >> 6)] = q; }
    __syncthreads();
    float st = sb[0] + sb[1] + sb[2] + sb[3];
    float qt = sb[4] + sb[5] + sb[6] + sb[7];
    __syncthreads();
    float mu = st * (1.f / 512.f);
    float rs = 1.f / sqrtf(qt * (1.f / 512.f) - mu * mu + 1e-5f);
    float na = (x0 - mu) * rs * g2[tid] + be2[tid];
    float nb = (x1 - mu) * rs * g2[tid + 256] + be2[tid + 256];
    float dd = na * w1[(size_t)tid * 2048 + col] + nb * w1[(size_t)(tid + 256) * 2048 + col];
    #pragma unroll
    for (int o = 1; o < 64; o <<= 1) dd += __shfl_xor(dd, o);
    if ((tid & 63) == 0) sb[tid >> 6] = dd;
    __syncthreads();
    if (tid == 0) {
      float hv = sb[0] + sb[1] + sb[2] + sb[3] + b1[col];
      if (hv >= 2.0f) { int ix = atomicAdd(&cnt[0], 1); if (ix < CAP) spikeL[ix] = v; }
    }
    __syncthreads();
  }
}

// out[row,:] += w2[col,:] for each spike
__global__ void k_apply(const float* __restrict__ w2, const int* __restrict__ cnt,
                        const unsigned* __restrict__ spikeL, float* __restrict__ out) {
  int n = cnt[0]; if (n > CAP) n = CAP;
  int tid = threadIdx.x;
  for (int e = blockIdx.x; e < n; e += gridDim.x) {
    unsigned v = spikeL[e];
    int row = (int)(v >> 11), col = (int)(v & 2047u);
    atomicAdd(&out[(size_t)row * 512 + tid * 2 + 0], w2[(size_t)col * 512 + tid * 2 + 0]);
    atomicAdd(&out[(size_t)row * 512 + tid * 2 + 1], w2[(size_t)col * 512 + tid * 2 + 1]);
  }
}

// ---------------- launch ----------------

extern "C" void kernel_launch(void* const* d_in, const int* in_sizes, int n_in,
                              void* d_out, int out_size, void* d_ws, size_t ws_size,
                              hipStream_t stream) {
  (void)in_sizes; (void)n_in; (void)out_size; (void)ws_size;
  const float* x   = (const float*)d_in[0];
  const float* wq  = (const float*)d_in[1];
  const float* bq  = (const float*)d_in[2];
  const float* wk  = (const float*)d_in[3];
  const float* bk  = (const float*)d_in[4];
  const float* wv  = (const float*)d_in[5];
  const float* bv  = (const float*)d_in[6];
  const float* w1  = (const float*)d_in[7];
  const float* b1  = (const float*)d_in[8];
  const float* w2  = (const float*)d_in[9];
  const float* b2  = (const float*)d_in[10];
  const float* g1  = (const float*)d_in[11];
  const float* be1 = (const float*)d_in[12];
  const float* g2  = (const float*)d_in[13];
  const float* be2 = (const float*)d_in[14];
  float* out = (float*)d_out;

  char* w = (char*)d_ws;
  size_t off = 0;
  auto take = [&](size_t bytes) { char* p = w + off; off += (bytes + 255) & ~(size_t)255; return p; };
  int*      cnt    = (int*)take(256);
  u16*      n1     = (u16*)take((size_t)ROWS * EMB * 2);
  u16*      wqkvT  = (u16*)take((size_t)1536 * 512 * 2);
  u16*      w1T    = (u16*)take((size_t)2048 * 512 * 2);
  u16*      Qb     = (u16*)take((size_t)MB * NH * SEQ * HD * 2);
  u16*      Kb     = (u16*)take((size_t)MB * NH * SEQ * HD * 2);
  u16*      Vtb    = (u16*)take((size_t)MB * NH * SEQ * HD * 2);
  u16*      att    = (u16*)take((size_t)ROWS * EMB * 2);
  float*    x2     = (float*)take((size_t)ROWS * EMB * 4);
  u16*      n2     = (u16*)take((size_t)ROWS * EMB * 2);
  unsigned* spikeL = (unsigned*)take((size_t)CAP * 4);
  unsigned* candL  = (unsigned*)take((size_t)CAP * 4);

  k_prep<<<3840, 256, 0, stream>>>(x, g1, be1, wq, wk, wv, w1, n1, wqkvT, w1T, cnt);
  k_gemm_qkv<<<dim3(12, 64), 256, 0, stream>>>(n1, wqkvT, bq, bk, bv, Qb, Kb, Vtb);
  k_flash<<<dim3(16, 8, 4), 256, 0, stream>>>(Qb, Kb, Vtb, att);
  k_ln2<<<ROWS / 4, 256, 0, stream>>>(x, att, g2, be2, b2, x2, n2, out);
  k_gemm_ffn1<<<dim3(16, 64), 256, 0, stream>>>(n2, w1T, b1, cnt, spikeL, candL);
  k_fixup<<<256, 256, 0, stream>>>(x2, w1, b1, g2, be2, cnt, spikeL, candL);
  k_apply<<<128, 256, 0, stream>>>(w2, cnt, spikeL, out);
}